// Round 8
// baseline (166.174 us; speedup 1.0000x reference)
//
#include <hip/hip_runtime.h>

#define BATCH 16
#define CH    16
#define HH    128
#define WW    128
#define NC    8            // n_convs
#define TR    8            // output rows per band
#define BPB   2            // bands per block (register prefetch across bands)
#define HR    (TR + 2)     // 10 halo rows
#define FW    (WW + 2)     // 130 halo cols
#define NELEM (HR * FW)    // 1300 staged elements per band
#define NTHR  256
#define NSTG  6            // ceil(1300/256)

// Per-element features: f0=silu(v), f1=tanh(v), f2=2t^2 (=T2+1), f3=T3=4t^3-3t.
// bias_j = sum_i (W0 - W2)[j,i] absorbs T0 and the +1 shift of f2, so features
// are exactly (0,0,0,0) at v=0 -> zero padding handled by feat(0)=0.
//
// Round-8: R7 refuted the occupancy theory (2x waves/CU, no change). Every
// round measures ~= SERIAL SUM of pipes (LDS ~36 + HBM ~22 + VALU ~18 us):
// cohort phase-lock means pipes barely overlap, so shrink the biggest serial
// term: LDS, 60% of which was 72 broadcast weight b128 reads PER THREAD per
// band (~12 cy each even for broadcast). Fix: weights read once per WAVE and
// moved to SGPRs via __builtin_amdgcn_readfirstlane (plain intrinsic — NOT
// R5's crashed hand-asm s_load); FMA = v_fmac vacc, s, vf (1 SGPR operand,
// legal). Wave w owns convs {2w,2w+1} so only 6 quads (~24 SGPR) are live
// per dc. Per-wave-band LDS: feat 60x12 + wgt 18x12 + writes ~= 1000 cy
// (was ~1360). TR=8 halves halo over-read; BPB=2 keeps R1's proven register
// prefetch (the only measured win: HBM hides under conv).
// Summation order per output (dc -> dr -> feat, f32) identical to R7.
// Regs: acc 32 + f[10] 40 + v 6 + misc ~15 ~= 93 -> (256,4), no spill.
__global__ __launch_bounds__(NTHR, 4)
void kan_conv_kernel(const float* __restrict__ x,
                     const float* __restrict__ cheby,   // (8,9,4)
                     const float* __restrict__ bwt,     // (8,9)
                     const float* __restrict__ scl,     // (8,9)
                     float* __restrict__ out)           // (16,128,128,128)
{
    __shared__ float4 feat[HR][FW];      // 20,800 B
    __shared__ float4 wgt[9 * NC];       // [tap*8 + j] = (bw, W1, W2, W3)
    __shared__ float  bias[NC];

    const int tid   = threadIdx.x;       // 0..255
    const int bz    = blockIdx.y;        // plane = b*CH + c
    const int band0 = blockIdx.x * (TR * BPB);
    const int lane  = tid & 63;          // col within half
    const int pp    = tid >> 6;          // wave id 0..3 -> convs 2pp, 2pp+1

    // ---- stage combined weights (once per block) ----
    if (tid < 9 * NC) {
        int j = tid / 9, i = tid % 9;
        float s = scl[j * 9 + i];
        wgt[i * NC + j] = make_float4(bwt[j * 9 + i],
                                      cheby[(j * 9 + i) * 4 + 1] * s,
                                      cheby[(j * 9 + i) * 4 + 2] * s,
                                      cheby[(j * 9 + i) * 4 + 3] * s);
    } else if (tid >= 128 && tid < 128 + NC) {
        int j = tid - 128;
        float b = 0.f;
        #pragma unroll
        for (int i = 0; i < 9; ++i)
            b += (cheby[(j * 9 + i) * 4 + 0] - cheby[(j * 9 + i) * 4 + 2]) * scl[j * 9 + i];
        bias[j] = b;
    }

    // ---- issue band-0 staging loads back-to-back into registers ----
    const float* xp = x + (size_t)bz * HH * WW;
    float v[NSTG];
    #pragma unroll
    for (int k = 0; k < NSTG; ++k) {
        int idx = tid + NTHR * k;
        int row = idx / FW;              // magic-mul div
        int col = idx - row * FW;
        int gh  = band0 + row - 1;
        int gw  = col - 1;
        float nv = 0.f;
        if (idx < NELEM && (unsigned)gh < (unsigned)HH && (unsigned)gw < (unsigned)WW)
            nv = xp[gh * WW + gw];       // 4B/lane coalesced
        v[k] = nv;
    }

    for (int bb = 0; bb < BPB; ++bb) {
        const int band = band0 + bb * TR;
        if (bb) __syncthreads();         // feat[] reuse guard

        // ---- features from prefetched registers -> LDS (16B/lane writes) ----
        #pragma unroll
        for (int k = 0; k < NSTG; ++k) {
            int idx = tid + NTHR * k;
            if (idx < NELEM) {
                int row = idx / FW;
                int col = idx - row * FW;
                float val = v[k];
                float e1 = __expf(val);
                float e2 = e1 * e1;                               // exp(2v)
                float sg = 1.f - __builtin_amdgcn_rcpf(1.f + e1); // sigmoid(v)
                float t  = 1.f - 2.f * __builtin_amdgcn_rcpf(e2 + 1.f); // tanh(v)
                float f2 = 2.f * t * t;                           // T2 + 1
                float f3 = 2.f * t * (f2 - 1.f) - t;              // T3
                feat[row][col] = make_float4(val * sg, t, f2, f3);
            }
        }
        __syncthreads();

        // ---- prefetch next band's x while this band's conv runs ----
        if (bb + 1 < BPB) {
            const int nb = band + TR;
            #pragma unroll
            for (int k = 0; k < NSTG; ++k) {
                int idx = tid + NTHR * k;
                int row = idx / FW;
                int col = idx - row * FW;
                int gh  = nb + row - 1;
                int gw  = col - 1;
                float nv = 0.f;
                if (idx < NELEM && (unsigned)gh < (unsigned)HH && (unsigned)gw < (unsigned)WW)
                    nv = xp[gh * WW + gw];
                v[k] = nv;
            }
        }

        // ---- conv: wave pp -> convs {2pp,2pp+1}; lane -> cols lane, lane+64;
        //      all 8 rows. acc[row][colhalf][convq] = 32 VGPRs ----
        float acc[TR][2][2];
        {
            float b0 = bias[pp * 2];     // uniform LDS broadcast
            float b1 = bias[pp * 2 + 1];
            #pragma unroll
            for (int s = 0; s < TR; ++s)
                #pragma unroll
                for (int h = 0; h < 2; ++h) {
                    acc[s][h][0] = b0;
                    acc[s][h][1] = b1;
                }
        }

        #pragma unroll
        for (int dc = 0; dc < 3; ++dc) {
            // 6 weight quads for this dc -> SGPRs (one wave-wide read each)
            float ws[3][2][4];
            #pragma unroll
            for (int dr = 0; dr < 3; ++dr)
                #pragma unroll
                for (int q = 0; q < 2; ++q) {
                    float4 wv = wgt[(dr * 3 + dc) * NC + pp * 2 + q];
                    ws[dr][q][0] = __uint_as_float(__builtin_amdgcn_readfirstlane(__float_as_uint(wv.x)));
                    ws[dr][q][1] = __uint_as_float(__builtin_amdgcn_readfirstlane(__float_as_uint(wv.y)));
                    ws[dr][q][2] = __uint_as_float(__builtin_amdgcn_readfirstlane(__float_as_uint(wv.z)));
                    ws[dr][q][3] = __uint_as_float(__builtin_amdgcn_readfirstlane(__float_as_uint(wv.w)));
                }
            #pragma unroll
            for (int h = 0; h < 2; ++h) {
                float4 f[HR];            // 40 VGPRs, scoped per half
                #pragma unroll
                for (int r = 0; r < HR; ++r)
                    f[r] = feat[r][h * 64 + lane + dc];   // 16B/lane: conflict-free
                #pragma unroll
                for (int dr = 0; dr < 3; ++dr)
                    #pragma unroll
                    for (int q = 0; q < 2; ++q)
                        #pragma unroll
                        for (int s = 0; s < TR; ++s) {
                            acc[s][h][q] += ws[dr][q][0] * f[s + dr].x;
                            acc[s][h][q] += ws[dr][q][1] * f[s + dr].y;
                            acc[s][h][q] += ws[dr][q][2] * f[s + dr].z;
                            acc[s][h][q] += ws[dr][q][3] * f[s + dr].w;
                        }
            }
        }

        // ---- store: per (q,s,h) each wave writes 64 consecutive floats ----
        float* op = out + (size_t)(bz * NC + pp * 2) * HH * WW
                        + (size_t)band * WW + lane;
        #pragma unroll
        for (int q = 0; q < 2; ++q)
            #pragma unroll
            for (int s = 0; s < TR; ++s)
                #pragma unroll
                for (int h = 0; h < 2; ++h)
                    op[(size_t)q * HH * WW + (size_t)s * WW + h * 64] = acc[s][h][q];
    }
}

extern "C" void kernel_launch(void* const* d_in, const int* in_sizes, int n_in,
                              void* d_out, int out_size, void* d_ws, size_t ws_size,
                              hipStream_t stream) {
    const float* x     = (const float*)d_in[0];
    const float* cheby = (const float*)d_in[1];
    const float* bwt   = (const float*)d_in[2];
    const float* scl   = (const float*)d_in[3];
    float* out = (float*)d_out;

    dim3 grid(HH / (TR * BPB), BATCH * CH);  // 8 x 256 = 2048 blocks
    dim3 block(NTHR);
    hipLaunchKernelGGL(kan_conv_kernel, grid, block, 0, stream, x, cheby, bwt, scl, out);
}